// Round 1
// baseline (214.936 us; speedup 1.0000x reference)
//
#include <hip/hip_runtime.h>
#include <math.h>

#define B_    64
#define A_    5
#define C_    80
#define GY_   32
#define GX_   32
#define N_    50
#define CH_   85
#define PLANE_ 1024   // GY*GX
#define NBOX_ 5120    // A*PLANE

__device__ __forceinline__ float sigmoidf_(float x) {
    return 1.0f / (1.0f + __expf(-x));
}

__device__ __forceinline__ float waveReduceSum(float v) {
    #pragma unroll
    for (int m = 32; m >= 1; m >>= 1) v += __shfl_xor(v, m, 64);
    return v;
}

__device__ __forceinline__ float waveReduceMax(float v) {
    #pragma unroll
    for (int m = 32; m >= 1; m >>= 1) v = fmaxf(v, __shfl_xor(v, m, 64));
    return v;
}

// Kernel 1: per-gt preprocessing. One thread per (b,n).
__global__ void k1_gt(const float* __restrict__ gt, const float* __restrict__ anc,
                      float4* __restrict__ gtbox, float4* __restrict__ enc,
                      int* __restrict__ clsb, int* __restrict__ bbox) {
    int t = blockIdx.x * blockDim.x + threadIdx.x;
    if (t >= B_ * N_) return;
    const float* g = gt + t * 7;
    float dx = g[0], dy = g[1], gxf = g[2], gyf = g[3], gw = g[4], gh = g[5];
    int cls = (int)g[6];

    // argmax over anchors of whcentered IOU (first-max wins, matches jnp.argmax)
    float best = -1.0f; int bp = 0;
    #pragma unroll
    for (int a = 0; a < A_; a++) {
        float aw = anc[2 * a], ah = anc[2 * a + 1];
        float inter = fminf(gw, aw) * fminf(gh, ah);
        float iou = inter / (gw * gh + aw * ah - inter);
        if (iou > best) { best = iou; bp = a; }
    }
    int gxi = (int)gxf, gyi = (int)gyf;
    bbox[t] = bp * PLANE_ + gyi * GX_ + gxi;

    float cx = dx + gxf / (float)GX_;
    float cy = dy + gyf / (float)GY_;
    gtbox[t] = make_float4(cx - gw * 0.5f, cy - gh * 0.5f, cx + gw * 0.5f, cy + gh * 0.5f);
    enc[t]   = make_float4(dx, dy, __logf(gw) - __logf(anc[2 * bp]),
                                   __logf(gh) - __logf(anc[2 * bp + 1]));
    clsb[t] = cls;
}

// Kernel 2: one thread per box. noobj + prior sums, iou_t side output.
// Grid: B*A*4 blocks of 256 (each block = quarter of one (b,a) 32x32 plane).
__global__ __launch_bounds__(256) void k2_main(
        const float* __restrict__ pred, const float* __restrict__ anc,
        const float4* __restrict__ gtbox, const int* __restrict__ bbox,
        const int* __restrict__ seen,
        float* __restrict__ iout, float* __restrict__ out) {
    __shared__ float4 sgt[N_];
    __shared__ int sbb[N_];
    int bid = blockIdx.x;
    int b = bid / 20; int r = bid - b * 20;
    int a = r >> 2; int chunk = r & 3;
    int tid = threadIdx.x;
    if (tid < N_) { sgt[tid] = gtbox[b * N_ + tid]; sbb[tid] = bbox[b * N_ + tid]; }
    __syncthreads();

    int spatial = chunk * 256 + tid;
    int gy = spatial >> 5, gx = spatial & 31;
    const float* p = pred + (size_t)(b * A_ + a) * CH_ * PLANE_ + spatial;
    float tx = p[0], ty = p[PLANE_], tw = p[2 * PLANE_], th = p[3 * PLANE_], to = p[4 * PLANE_];
    float sx = sigmoidf_(tx), sy = sigmoidf_(ty), so = sigmoidf_(to);

    float pcx = sx + (float)gx / (float)GX_;
    float pcy = sy + (float)gy / (float)GY_;
    float pw = anc[2 * a] * __expf(tw);
    float ph = anc[2 * a + 1] * __expf(th);
    float px1 = pcx - pw * 0.5f, py1 = pcy - ph * 0.5f;
    float px2 = pcx + pw * 0.5f, py2 = pcy + ph * 0.5f;
    float areap = pw * ph;

    int myIdx = a * PLANE_ + spatial;
    float maxIou = 0.0f;
    bool isBest = false;
    for (int n = 0; n < N_; n++) {
        float4 gb = sgt[n];
        float ix = fmaxf(fminf(gb.z, px2) - fmaxf(gb.x, px1), 0.0f);
        float iy = fmaxf(fminf(gb.w, py2) - fmaxf(gb.y, py1), 0.0f);
        float inter = ix * iy;
        float areag = (gb.z - gb.x) * (gb.w - gb.y);
        float iou = inter / (areag + areap - inter);
        maxIou = fmaxf(maxIou, iou);
        if (sbb[n] == myIdx) { isBest = true; iout[b * N_ + n] = iou; }
    }

    // posf: 1 if best-box target, else 2 if overlap>0.6, else 0
    float noobj = (!isBest && !(maxIou > 0.6f)) ? so * so : 0.0f;
    float contrib = noobj;  // LAMBDA_NOOBJ = 1.0
    if (seen[0] < 12800) {
        if (!isBest) {
            float d0 = sx - 0.015625f, d1 = sy - 0.015625f;  // 0.5/32
            contrib += 0.01f * (d0 * d0 + d1 * d1 + tw * tw + th * th);  // LAMBDA_PRIOR
        }
    }

    contrib = waveReduceSum(contrib);
    __shared__ float part[4];
    int wid = tid >> 6, lid = tid & 63;
    if (lid == 0) part[wid] = contrib;
    __syncthreads();
    if (tid == 0) atomicAdd(out, part[0] + part[1] + part[2] + part[3]);
}

// Kernel 3: one wave per gt. Gather 85 channels at best_box, softmax over 80
// classes, cls + coord + obj terms.
__global__ __launch_bounds__(64) void k3_gather(
        const float* __restrict__ pred,
        const float4* __restrict__ enc, const int* __restrict__ clsb,
        const int* __restrict__ bbox, const float* __restrict__ iout,
        float* __restrict__ out) {
    int t = blockIdx.x;            // 0 .. B*N-1
    int b = t / N_;
    int bb = bbox[t];
    int a = bb >> 10, spatial = bb & 1023;
    const float* p = pred + (size_t)(b * A_ + a) * CH_ * PLANE_ + spatial;
    int lane = threadIdx.x;

    // class logits: channels 5..84 -> class c at channel 5+c
    float z1 = p[(5 + lane) * PLANE_];
    float z2 = (lane < 16) ? p[(69 + lane) * PLANE_] : -1e30f;
    float m = waveReduceMax(fmaxf(z1, z2));
    float e1 = __expf(z1 - m);
    float e2 = (lane < 16) ? __expf(z2 - m) : 0.0f;
    float S = waveReduceSum(e1 + e2);
    float inv = 1.0f / S;

    int cls = clsb[t];
    float s1 = e1 * inv;
    float d1 = s1 - ((lane == cls) ? 1.0f : 0.0f);
    float term = d1 * d1;
    if (lane < 16) {
        float s2 = e2 * inv;
        float d2 = s2 - (((64 + lane) == cls) ? 1.0f : 0.0f);
        term += d2 * d2;
    }
    float clsSum = waveReduceSum(term);

    if (lane == 0) {
        float tx = p[0], ty = p[PLANE_], tw = p[2 * PLANE_], th = p[3 * PLANE_], to = p[4 * PLANE_];
        float4 e = enc[t];
        float c0 = sigmoidf_(tx) - e.x;
        float c1 = sigmoidf_(ty) - e.y;
        float c2 = tw - e.z;
        float c3 = th - e.w;
        float coord = c0 * c0 + c1 * c1 + c2 * c2 + c3 * c3;  // LAMBDA_COORD = 1
        float ot = sigmoidf_(to) - iout[t];
        atomicAdd(out, clsSum + coord + 5.0f * ot * ot);      // LAMBDA_OBJ = 5
    }
}

extern "C" void kernel_launch(void* const* d_in, const int* in_sizes, int n_in,
                              void* d_out, int out_size, void* d_ws, size_t ws_size,
                              hipStream_t stream) {
    const float* pred = (const float*)d_in[0];
    const float* gt   = (const float*)d_in[1];
    const float* anc  = (const float*)d_in[2];
    const int*   seen = (const int*)d_in[3];
    float* out = (float*)d_out;

    // workspace layout (d_ws is >= 140.8 KB; poisoned 0xAA each call, all
    // regions below are fully written before being read)
    char* w = (char*)d_ws;
    float4* gtbox = (float4*)w;  w += sizeof(float4) * B_ * N_;
    float4* enc   = (float4*)w;  w += sizeof(float4) * B_ * N_;
    int*    clsb  = (int*)w;     w += sizeof(int) * B_ * N_;
    int*    bbox  = (int*)w;     w += sizeof(int) * B_ * N_;
    float*  iout  = (float*)w;   w += sizeof(float) * B_ * N_;

    hipMemsetAsync(d_out, 0, sizeof(float), stream);
    k1_gt<<<(B_ * N_ + 255) / 256, 256, 0, stream>>>(gt, anc, gtbox, enc, clsb, bbox);
    k2_main<<<B_ * A_ * 4, 256, 0, stream>>>(pred, anc, gtbox, bbox, seen, iout, out);
    k3_gather<<<B_ * N_, 64, 0, stream>>>(pred, enc, clsb, bbox, iout, out);
}

// Round 2
// 165.936 us; speedup vs baseline: 1.2953x; 1.2953x over previous
//
#include <hip/hip_runtime.h>
#include <math.h>

#define B_    64
#define A_    5
#define C_    80
#define GY_   32
#define GX_   32
#define N_    50
#define CH_   85
#define PLANE_ 1024   // GY*GX
#define NBLK_ (B_ * A_ * 4)   // 1280 blocks, 256 threads each: one thread per box

__device__ __forceinline__ float sigmoidf_(float x) {
    return 1.0f / (1.0f + __expf(-x));
}

__device__ __forceinline__ float waveReduceSum(float v) {
    #pragma unroll
    for (int m = 32; m >= 1; m >>= 1) v += __shfl_xor(v, m, 64);
    return v;
}

__device__ __forceinline__ float waveReduceMax(float v) {
    #pragma unroll
    for (int m = 32; m >= 1; m >>= 1) v = fmaxf(v, __shfl_xor(v, m, 64));
    return v;
}

// Fused kernel: everything except the final 1280-way partial reduction.
// Block (b, a, chunk): 256 threads = quarter of one (b,a) 32x32 plane.
__global__ __launch_bounds__(256) void yolo_fused(
        const float* __restrict__ pred, const float* __restrict__ gt,
        const float* __restrict__ anc, const int* __restrict__ seen,
        float* __restrict__ partial) {
    __shared__ float4 sgt[N_];    // gt boxes, xyxy
    __shared__ float4 senc[N_];   // regression targets (dx, dy, log ratios)
    __shared__ int    sbb[N_];    // best-box flat index (a*1024 + gy*32 + gx)
    __shared__ int    scls[N_];   // class id

    int bid = blockIdx.x;
    int b = bid / 20; int r = bid - b * 20;
    int a = r >> 2; int chunk = r & 3;
    int tid = threadIdx.x;

    // Phase 0: per-gt preprocessing (redundant per block; 50x ~30 flops)
    if (tid < N_) {
        const float* g = gt + (b * N_ + tid) * 7;
        float dx = g[0], dy = g[1], gxf = g[2], gyf = g[3], gw = g[4], gh = g[5];
        // argmax over anchors of wh-centered IOU (first-max wins = jnp.argmax)
        float best = -1.0f; int bp = 0;
        #pragma unroll
        for (int aa = 0; aa < A_; aa++) {
            float aw = anc[2 * aa], ah = anc[2 * aa + 1];
            float inter = fminf(gw, aw) * fminf(gh, ah);
            float iou = inter / (gw * gh + aw * ah - inter);
            if (iou > best) { best = iou; bp = aa; }
        }
        sbb[tid] = bp * PLANE_ + (int)gyf * GX_ + (int)gxf;
        float cx = dx + gxf / (float)GX_;
        float cy = dy + gyf / (float)GY_;
        sgt[tid]  = make_float4(cx - gw * 0.5f, cy - gh * 0.5f,
                                cx + gw * 0.5f, cy + gh * 0.5f);
        senc[tid] = make_float4(dx, dy, __logf(gw) - __logf(anc[2 * bp]),
                                        __logf(gh) - __logf(anc[2 * bp + 1]));
        scls[tid] = (int)g[6];
    }
    __syncthreads();

    // Phase 1: per-box work (coalesced channel-plane loads)
    int spatial = chunk * 256 + tid;
    int gy = spatial >> 5, gx = spatial & 31;
    const float* p = pred + (size_t)(b * A_ + a) * CH_ * PLANE_ + spatial;
    float tx = p[0], ty = p[PLANE_], tw = p[2 * PLANE_],
          th = p[3 * PLANE_], to = p[4 * PLANE_];
    float sx = sigmoidf_(tx), sy = sigmoidf_(ty), so = sigmoidf_(to);

    float pcx = sx + (float)gx / (float)GX_;
    float pcy = sy + (float)gy / (float)GY_;
    float pw = anc[2 * a] * __expf(tw);
    float ph = anc[2 * a + 1] * __expf(th);
    float px1 = pcx - pw * 0.5f, py1 = pcy - ph * 0.5f;
    float px2 = pcx + pw * 0.5f, py2 = pcy + ph * 0.5f;
    float areap = pw * ph;

    int myIdx = a * PLANE_ + spatial;
    float maxIou = 0.0f;
    bool isBest = false;
    for (int n = 0; n < N_; n++) {
        float4 gb = sgt[n];
        float ix = fmaxf(fminf(gb.z, px2) - fmaxf(gb.x, px1), 0.0f);
        float iy = fmaxf(fminf(gb.w, py2) - fmaxf(gb.y, py1), 0.0f);
        float inter = ix * iy;
        float areag = (gb.z - gb.x) * (gb.w - gb.y);
        float iou = inter / (areag + areap - inter);
        maxIou = fmaxf(maxIou, iou);
        isBest = isBest || (sbb[n] == myIdx);
    }

    // posf: 1 if best-box target (overrides the 2.0), else 2 if iou>0.6, else 0
    float acc = (!isBest && !(maxIou > 0.6f)) ? so * so : 0.0f;  // LAMBDA_NOOBJ=1
    if (seen[0] < 12800 && !isBest) {
        float d0 = sx - 0.015625f, d1 = sy - 0.015625f;  // 0.5/32
        acc += 0.01f * (d0 * d0 + d1 * d1 + tw * tw + th * th);  // LAMBDA_PRIOR
    }

    // Phase 2: per-wave epilogue — gts whose best box lives in this wave.
    // At most one thread grid-wide matches a given (b,n); mask is wave-uniform.
    int lane = tid & 63;
    for (int n = 0; n < N_; n++) {
        int bbn = sbb[n];
        bool own = (bbn == myIdx);
        unsigned long long mask = __ballot(own);
        if (mask == 0ULL) continue;
        int owner = (int)__ffsll((long long)mask) - 1;
        int sp = __shfl(spatial, owner, 64);

        // Wave-cooperative softmax over 80 class channels at the owner's cell.
        float z1 = p[(5 + lane) * PLANE_ + (sp - spatial)];
        float z2 = (lane < 16) ? p[(69 + lane) * PLANE_ + (sp - spatial)] : -1e30f;
        float m = waveReduceMax(fmaxf(z1, z2));
        float e1 = __expf(z1 - m);
        float e2 = (lane < 16) ? __expf(z2 - m) : 0.0f;
        float S = waveReduceSum(e1 + e2);
        float inv = 1.0f / S;

        int cls = scls[n];
        float s1 = e1 * inv;
        float d1 = s1 - ((lane == cls) ? 1.0f : 0.0f);
        float term = d1 * d1;
        if (lane < 16) {
            float s2 = e2 * inv;
            float d2 = s2 - (((64 + lane) == cls) ? 1.0f : 0.0f);
            term += d2 * d2;
        }
        float clsSum = waveReduceSum(term);

        if (own) {
            // iou_t: IOU(gt n, my pbox) — recompute (few flops)
            float4 gb = sgt[n];
            float ix = fmaxf(fminf(gb.z, px2) - fmaxf(gb.x, px1), 0.0f);
            float iy = fmaxf(fminf(gb.w, py2) - fmaxf(gb.y, py1), 0.0f);
            float inter = ix * iy;
            float areag = (gb.z - gb.x) * (gb.w - gb.y);
            float iou_t = inter / (areag + areap - inter);

            float4 e = senc[n];
            float c0 = sx - e.x, c1 = sy - e.y, c2 = tw - e.z, c3 = th - e.w;
            float coord = c0 * c0 + c1 * c1 + c2 * c2 + c3 * c3;  // LAMBDA_COORD=1
            float ot = so - iou_t;
            acc += clsSum + coord + 5.0f * ot * ot;               // LAMBDA_OBJ=5
        }
    }

    // Block reduction -> one partial per block (no atomics)
    acc = waveReduceSum(acc);
    __shared__ float part[4];
    if (lane == 0) part[tid >> 6] = acc;
    __syncthreads();
    if (tid == 0) partial[bid] = part[0] + part[1] + part[2] + part[3];
}

// Final reduction: 1280 partials -> scalar. One block.
__global__ __launch_bounds__(256) void yolo_reduce(
        const float* __restrict__ partial, float* __restrict__ out) {
    int tid = threadIdx.x;
    float v = 0.0f;
    #pragma unroll
    for (int i = 0; i < 5; i++) v += partial[tid + 256 * i];
    v = waveReduceSum(v);
    __shared__ float part[4];
    if ((tid & 63) == 0) part[tid >> 6] = v;
    __syncthreads();
    if (tid == 0) out[0] = part[0] + part[1] + part[2] + part[3];
}

extern "C" void kernel_launch(void* const* d_in, const int* in_sizes, int n_in,
                              void* d_out, int out_size, void* d_ws, size_t ws_size,
                              hipStream_t stream) {
    const float* pred = (const float*)d_in[0];
    const float* gt   = (const float*)d_in[1];
    const float* anc  = (const float*)d_in[2];
    const int*   seen = (const int*)d_in[3];
    float* out = (float*)d_out;
    float* partial = (float*)d_ws;   // 1280 floats; fully written before read

    yolo_fused<<<NBLK_, 256, 0, stream>>>(pred, gt, anc, seen, partial);
    yolo_reduce<<<1, 256, 0, stream>>>(partial, out);
}

// Round 3
// 161.696 us; speedup vs baseline: 1.3293x; 1.0262x over previous
//
#include <hip/hip_runtime.h>
#include <math.h>

#define B_    64
#define A_    5
#define C_    80
#define GY_   32
#define GX_   32
#define N_    50
#define CH_   85
#define PLANE_ 1024   // GY*GX
#define NBLK_ (B_ * A_ * 4)   // 1280 blocks x 256 threads: one thread per box

__device__ __forceinline__ float sigmoidf_(float x) {
    return 1.0f / (1.0f + __expf(-x));
}

__device__ __forceinline__ float waveReduceSum(float v) {
    #pragma unroll
    for (int m = 32; m >= 1; m >>= 1) v += __shfl_xor(v, m, 64);
    return v;
}

__device__ __forceinline__ float waveReduceMax(float v) {
    #pragma unroll
    for (int m = 32; m >= 1; m >>= 1) v = fmaxf(v, __shfl_xor(v, m, 64));
    return v;
}

// Fused kernel. Block (b, a, chunk): 256 threads = quarter of a 32x32 plane.
__global__ __launch_bounds__(256) void yolo_fused(
        const float* __restrict__ pred, const float* __restrict__ gt,
        const float* __restrict__ anc, const int* __restrict__ seen,
        float* __restrict__ partial) {
    __shared__ float4 sgt[N_];    // gt boxes, xyxy
    __shared__ float  sga[N_];    // 0.375 * gt area  (iou>0.6 <=> inter>0.375*(Ag+Ap))
    __shared__ float4 senc[N_];   // regression targets
    __shared__ int    sbb[N_];    // best-box flat index (a*1024 + gy*32 + gx)
    __shared__ int    scls[N_];   // class id
    __shared__ int    slist[N_];  // gts whose best box lives in THIS block
    __shared__ int    scnt;

    int bid = blockIdx.x;
    int b = bid / 20; int r = bid - b * 20;
    int a = r >> 2; int chunk = r & 3;
    int tid = threadIdx.x;
    if (tid == 0) scnt = 0;
    __syncthreads();

    // Phase 0: per-gt preprocessing (one lane per gt) + owner-list build
    if (tid < N_) {
        const float* g = gt + (b * N_ + tid) * 7;
        float dx = g[0], dy = g[1], gxf = g[2], gyf = g[3], gw = g[4], gh = g[5];
        float best = -1.0f; int bp = 0;
        #pragma unroll
        for (int aa = 0; aa < A_; aa++) {
            float aw = anc[2 * aa], ah = anc[2 * aa + 1];
            float inter = fminf(gw, aw) * fminf(gh, ah);
            float iou = inter / (gw * gh + aw * ah - inter);
            if (iou > best) { best = iou; bp = aa; }   // first-max wins = jnp.argmax
        }
        int bb = bp * PLANE_ + (int)gyf * GX_ + (int)gxf;
        sbb[tid] = bb;
        float cx = dx + gxf * (1.0f / 32.0f);
        float cy = dy + gyf * (1.0f / 32.0f);
        sgt[tid]  = make_float4(cx - gw * 0.5f, cy - gh * 0.5f,
                                cx + gw * 0.5f, cy + gh * 0.5f);
        sga[tid]  = 0.375f * gw * gh;
        senc[tid] = make_float4(dx, dy, __logf(gw) - __logf(anc[2 * bp]),
                                        __logf(gh) - __logf(anc[2 * bp + 1]));
        scls[tid] = (int)g[6];
        // does this gt's best box fall in this block's (a, chunk) range?
        if ((bb >> 10) == a && ((bb & 1023) >> 8) == chunk) {
            int slot = atomicAdd(&scnt, 1);
            slist[slot] = tid;
        }
    }
    __syncthreads();

    // Phase 1: per-box work (coalesced plane loads), division-free overlap test
    int spatial = chunk * 256 + tid;
    int gy = spatial >> 5, gx = spatial & 31;
    const float* pb = pred + (size_t)(b * A_ + a) * (CH_ * PLANE_);
    const float* p = pb + spatial;
    float tx = p[0], ty = p[PLANE_], tw = p[2 * PLANE_],
          th = p[3 * PLANE_], to = p[4 * PLANE_];
    float sx = sigmoidf_(tx), sy = sigmoidf_(ty), so = sigmoidf_(to);

    float pcx = sx + (float)gx * (1.0f / 32.0f);
    float pcy = sy + (float)gy * (1.0f / 32.0f);
    float pw = anc[2 * a] * __expf(tw);
    float ph = anc[2 * a + 1] * __expf(th);
    float px1 = pcx - pw * 0.5f, py1 = pcy - ph * 0.5f;
    float px2 = pcx + pw * 0.5f, py2 = pcy + ph * 0.5f;
    float areap = pw * ph;
    float a375p = 0.375f * areap;

    bool anyHigh = false;
    #pragma unroll 10
    for (int n = 0; n < N_; n++) {
        float4 gb = sgt[n];
        float ix = fmaxf(fminf(gb.z, px2) - fmaxf(gb.x, px1), 0.0f);
        float iy = fmaxf(fminf(gb.w, py2) - fmaxf(gb.y, py1), 0.0f);
        // iou > 0.6  <=>  inter > 0.375*(areag + areap)
        anyHigh = anyHigh || (ix * iy > sga[n] + a375p);
    }

    // Phase 2: only gts in this block's owner list (avg ~2.5 entries)
    int lane = tid & 63;
    int myIdx = a * PLANE_ + spatial;
    bool isBest = false;
    float acc = 0.0f;
    int cnt = scnt;
    for (int i = 0; i < cnt; i++) {
        int n = slist[i];
        int bbn = sbb[n];
        bool own = (bbn == myIdx);
        isBest = isBest || own;
        unsigned long long mask = __ballot(own);
        if (mask == 0ULL) continue;           // owner is in another wave
        int sp = bbn & 1023;

        // wave-cooperative softmax over 80 class channels at the owner's cell
        float z1 = pb[(5 + lane) * PLANE_ + sp];
        float z2 = (lane < 16) ? pb[(69 + lane) * PLANE_ + sp] : -1e30f;
        float m = waveReduceMax(fmaxf(z1, z2));
        float e1 = __expf(z1 - m);
        float e2 = (lane < 16) ? __expf(z2 - m) : 0.0f;
        float S = waveReduceSum(e1 + e2);
        float inv = 1.0f / S;

        int cls = scls[n];
        float d1 = e1 * inv - ((lane == cls) ? 1.0f : 0.0f);
        float term = d1 * d1;
        if (lane < 16) {
            float d2 = e2 * inv - (((64 + lane) == cls) ? 1.0f : 0.0f);
            term += d2 * d2;
        }
        float clsSum = waveReduceSum(term);

        if (own) {
            float4 gb = sgt[n];
            float ix = fmaxf(fminf(gb.z, px2) - fmaxf(gb.x, px1), 0.0f);
            float iy = fmaxf(fminf(gb.w, py2) - fmaxf(gb.y, py1), 0.0f);
            float inter = ix * iy;
            float areag = (gb.z - gb.x) * (gb.w - gb.y);
            float iou_t = inter / (areag + areap - inter);

            float4 e = senc[n];
            float c0 = sx - e.x, c1 = sy - e.y, c2 = tw - e.z, c3 = th - e.w;
            float ot = so - iou_t;
            acc += clsSum + c0 * c0 + c1 * c1 + c2 * c2 + c3 * c3
                 + 5.0f * ot * ot;                         // LAMBDA_OBJ=5
        }
    }

    // noobj + prior (posf: 1 if best box, else 2 if overlap>0.6, else 0)
    if (!isBest) {
        if (!anyHigh) acc += so * so;                      // LAMBDA_NOOBJ=1
        if (seen[0] < 12800) {
            float d0 = sx - 0.015625f, d1 = sy - 0.015625f; // 0.5/32
            acc += 0.01f * (d0 * d0 + d1 * d1 + tw * tw + th * th); // LAMBDA_PRIOR
        }
    }

    // Block reduction -> one partial per block (no global atomics)
    acc = waveReduceSum(acc);
    __shared__ float part[4];
    if (lane == 0) part[tid >> 6] = acc;
    __syncthreads();
    if (tid == 0) partial[bid] = part[0] + part[1] + part[2] + part[3];
}

// Final reduction: 1280 partials -> scalar. One block.
__global__ __launch_bounds__(256) void yolo_reduce(
        const float* __restrict__ partial, float* __restrict__ out) {
    int tid = threadIdx.x;
    float v = 0.0f;
    #pragma unroll
    for (int i = 0; i < 5; i++) v += partial[tid + 256 * i];
    v = waveReduceSum(v);
    __shared__ float part[4];
    if ((tid & 63) == 0) part[tid >> 6] = v;
    __syncthreads();
    if (tid == 0) out[0] = part[0] + part[1] + part[2] + part[3];
}

extern "C" void kernel_launch(void* const* d_in, const int* in_sizes, int n_in,
                              void* d_out, int out_size, void* d_ws, size_t ws_size,
                              hipStream_t stream) {
    const float* pred = (const float*)d_in[0];
    const float* gt   = (const float*)d_in[1];
    const float* anc  = (const float*)d_in[2];
    const int*   seen = (const int*)d_in[3];
    float* out = (float*)d_out;
    float* partial = (float*)d_ws;   // 1280 floats; fully written before read

    yolo_fused<<<NBLK_, 256, 0, stream>>>(pred, gt, anc, seen, partial);
    yolo_reduce<<<1, 256, 0, stream>>>(partial, out);
}

// Round 4
// 160.603 us; speedup vs baseline: 1.3383x; 1.0068x over previous
//
#include <hip/hip_runtime.h>
#include <math.h>

#define B_    64
#define A_    5
#define C_    80
#define GY_   32
#define GX_   32
#define N_    50
#define CH_   85
#define PLANE_ 1024   // GY*GX
#define NBLK_ (B_ * A_ * 4)   // 1280 blocks x 256 threads: one thread per box

__device__ __forceinline__ float sigmoidf_(float x) {
    return 1.0f / (1.0f + __expf(-x));
}

__device__ __forceinline__ float waveReduceSum(float v) {
    #pragma unroll
    for (int m = 32; m >= 1; m >>= 1) v += __shfl_xor(v, m, 64);
    return v;
}

__device__ __forceinline__ float waveReduceMax(float v) {
    #pragma unroll
    for (int m = 32; m >= 1; m >>= 1) v = fmaxf(v, __shfl_xor(v, m, 64));
    return v;
}

// Fused kernel. Block (b, a, chunk): 256 threads = quarter of a 32x32 plane.
// Single __syncthreads in the main path: global channel loads are issued
// BEFORE phase 0 so their ~900-cycle HBM latency overlaps the gt prep.
__global__ __launch_bounds__(256) void yolo_fused(
        const float* __restrict__ pred, const float* __restrict__ gt,
        const float* __restrict__ anc, const int* __restrict__ seen,
        float* __restrict__ partial) {
    __shared__ float4 sgt[N_];    // gt boxes, xyxy
    __shared__ float  sga[N_];    // 0.375 * gt area (iou>0.6 <=> inter>0.375*(Ag+Ap))
    __shared__ float4 senc[N_];   // regression targets
    __shared__ int    sbb[N_];    // best-box flat index (a*1024 + gy*32 + gx)
    __shared__ int    scls[N_];   // class id
    __shared__ int    slist[N_];  // gts whose best box lives in THIS block
    __shared__ int    scnt;

    int bid = blockIdx.x;
    int b = bid / 20; int r = bid - b * 20;
    int a = r >> 2; int chunk = r & 3;
    int tid = threadIdx.x;

    // Issue the 5 coalesced channel-plane loads up front (latency overlap).
    int spatial = chunk * 256 + tid;
    int gy = spatial >> 5, gx = spatial & 31;
    const float* pb = pred + (size_t)(b * A_ + a) * (CH_ * PLANE_);
    const float* p = pb + spatial;
    float tx = p[0], ty = p[PLANE_], tw = p[2 * PLANE_],
          th = p[3 * PLANE_], to = p[4 * PLANE_];
    int seen0 = seen[0];

    // Phase 0: per-gt preprocessing — entirely in wave 0 (tid<50).
    // Owner list built with ballot + prefix-popcount (no LDS atomic, no init).
    if (tid < N_) {
        const float* g = gt + (b * N_ + tid) * 7;
        float dx = g[0], dy = g[1], gxf = g[2], gyf = g[3], gw = g[4], gh = g[5];
        float best = -1.0f; int bp = 0;
        #pragma unroll
        for (int aa = 0; aa < A_; aa++) {
            float aw = anc[2 * aa], ah = anc[2 * aa + 1];
            float inter = fminf(gw, aw) * fminf(gh, ah);
            float iou = inter / (gw * gh + aw * ah - inter);
            if (iou > best) { best = iou; bp = aa; }   // first-max wins = jnp.argmax
        }
        int bb = bp * PLANE_ + (int)gyf * GX_ + (int)gxf;
        sbb[tid] = bb;
        float cx = dx + gxf * (1.0f / 32.0f);
        float cy = dy + gyf * (1.0f / 32.0f);
        sgt[tid]  = make_float4(cx - gw * 0.5f, cy - gh * 0.5f,
                                cx + gw * 0.5f, cy + gh * 0.5f);
        sga[tid]  = 0.375f * gw * gh;
        senc[tid] = make_float4(dx, dy, __logf(gw) - __logf(anc[2 * bp]),
                                        __logf(gh) - __logf(anc[2 * bp + 1]));
        scls[tid] = (int)g[6];
        // owner-list: gts whose best box falls in this block's (a, chunk) range
        bool ownHere = ((bb >> 10) == a) && (((bb & 1023) >> 8) == chunk);
        unsigned long long mask = __ballot(ownHere);   // lanes >=50 inactive -> 0
        if (ownHere) {
            int slot = __popcll(mask & ((1ULL << tid) - 1ULL));
            slist[slot] = tid;
        }
        if (tid == 0) scnt = (int)__popcll(mask);
    }
    __syncthreads();

    // Phase 1: per-box work, division-free overlap test.
    float sx = sigmoidf_(tx), sy = sigmoidf_(ty), so = sigmoidf_(to);
    float pcx = sx + (float)gx * (1.0f / 32.0f);
    float pcy = sy + (float)gy * (1.0f / 32.0f);
    float pw = anc[2 * a] * __expf(tw);
    float ph = anc[2 * a + 1] * __expf(th);
    float px1 = pcx - pw * 0.5f, py1 = pcy - ph * 0.5f;
    float px2 = pcx + pw * 0.5f, py2 = pcy + ph * 0.5f;
    float areap = pw * ph;
    float a375p = 0.375f * areap;

    bool anyHigh = false;
    #pragma unroll 10
    for (int n = 0; n < N_; n++) {
        float4 gb = sgt[n];
        float ix = fmaxf(fminf(gb.z, px2) - fmaxf(gb.x, px1), 0.0f);
        float iy = fmaxf(fminf(gb.w, py2) - fmaxf(gb.y, py1), 0.0f);
        // iou > 0.6  <=>  ix*iy - 0.375*areap > 0.375*areag
        anyHigh = anyHigh || (__builtin_fmaf(ix, iy, -a375p) > sga[n]);
    }

    // Phase 2: only gts in this block's owner list (avg ~2.5 entries)
    int lane = tid & 63;
    int myIdx = a * PLANE_ + spatial;
    bool isBest = false;
    float acc = 0.0f;
    int cnt = scnt;
    for (int i = 0; i < cnt; i++) {
        int n = slist[i];
        int bbn = sbb[n];
        bool own = (bbn == myIdx);
        isBest = isBest || own;
        unsigned long long mask = __ballot(own);
        if (mask == 0ULL) continue;           // owner is in another wave
        int sp = bbn & 1023;

        // wave-cooperative softmax over 80 class channels at the owner's cell
        float z1 = pb[(5 + lane) * PLANE_ + sp];
        float z2 = (lane < 16) ? pb[(69 + lane) * PLANE_ + sp] : -1e30f;
        float m = waveReduceMax(fmaxf(z1, z2));
        float e1 = __expf(z1 - m);
        float e2 = (lane < 16) ? __expf(z2 - m) : 0.0f;
        float S = waveReduceSum(e1 + e2);
        float inv = 1.0f / S;

        int cls = scls[n];
        float d1 = e1 * inv - ((lane == cls) ? 1.0f : 0.0f);
        float term = d1 * d1;
        if (lane < 16) {
            float d2 = e2 * inv - (((64 + lane) == cls) ? 1.0f : 0.0f);
            term += d2 * d2;
        }
        float clsSum = waveReduceSum(term);

        if (own) {
            float4 gb = sgt[n];
            float ix = fmaxf(fminf(gb.z, px2) - fmaxf(gb.x, px1), 0.0f);
            float iy = fmaxf(fminf(gb.w, py2) - fmaxf(gb.y, py1), 0.0f);
            float inter = ix * iy;
            float areag = (gb.z - gb.x) * (gb.w - gb.y);
            float iou_t = inter / (areag + areap - inter);

            float4 e = senc[n];
            float c0 = sx - e.x, c1 = sy - e.y, c2 = tw - e.z, c3 = th - e.w;
            float ot = so - iou_t;
            acc += clsSum + c0 * c0 + c1 * c1 + c2 * c2 + c3 * c3
                 + 5.0f * ot * ot;                         // LAMBDA_OBJ=5
        }
    }

    // noobj + prior (posf: 1 if best box, else 2 if overlap>0.6, else 0)
    if (!isBest) {
        if (!anyHigh) acc += so * so;                      // LAMBDA_NOOBJ=1
        if (seen0 < 12800) {
            float d0 = sx - 0.015625f, d1 = sy - 0.015625f; // 0.5/32
            acc += 0.01f * (d0 * d0 + d1 * d1 + tw * tw + th * th); // LAMBDA_PRIOR
        }
    }

    // Block reduction -> one partial per block (no global atomics)
    acc = waveReduceSum(acc);
    __shared__ float part[4];
    if (lane == 0) part[tid >> 6] = acc;
    __syncthreads();
    if (tid == 0) partial[bid] = part[0] + part[1] + part[2] + part[3];
}

// Final reduction: 1280 partials -> scalar. One block of 320 threads, float4.
__global__ __launch_bounds__(320) void yolo_reduce(
        const float* __restrict__ partial, float* __restrict__ out) {
    int tid = threadIdx.x;
    float4 v4 = ((const float4*)partial)[tid];   // 320 * 4 = 1280
    float v = (v4.x + v4.y) + (v4.z + v4.w);
    v = waveReduceSum(v);
    __shared__ float part[5];
    if ((tid & 63) == 0) part[tid >> 6] = v;
    __syncthreads();
    if (tid == 0) out[0] = part[0] + part[1] + part[2] + part[3] + part[4];
}

extern "C" void kernel_launch(void* const* d_in, const int* in_sizes, int n_in,
                              void* d_out, int out_size, void* d_ws, size_t ws_size,
                              hipStream_t stream) {
    const float* pred = (const float*)d_in[0];
    const float* gt   = (const float*)d_in[1];
    const float* anc  = (const float*)d_in[2];
    const int*   seen = (const int*)d_in[3];
    float* out = (float*)d_out;
    float* partial = (float*)d_ws;   // 1280 floats; fully written before read

    yolo_fused<<<NBLK_, 256, 0, stream>>>(pred, gt, anc, seen, partial);
    yolo_reduce<<<1, 320, 0, stream>>>(partial, out);
}